// Round 24
// baseline (16.284 us; speedup 1.0000x reference)
//
#include <hip/hip_runtime.h>

// DLGN_VT v22 — v18 base + phase-2 re-tiled to (8i x 4j x 4k) per thread:
//   cuts phase-2 LDS reads 80 -> 32 per thread (g1 becomes wave-uniform 2xf4;
//   g2/g3 one f4 each, 8-addr multicast) at +15 VALU/b. Same V footprint
//   (32 float4/thread), same coalescing class, same Plds reduction.
//   512 blocks x 256 thr, 8 rows/block, launch_bounds(256,2). LDS 18.6 KB.
//   Phase 1 (= v18): W1/2/3 chunks in 48 regs; x kc-skewed in LDS; 8 rows x 24
//   pk-FMA; pure-DPP combine; sigmoid -> Gs[8][100]. V issued after phase-1 FMA.
// No atomics, no memset, no global scratch.

#define BETA 30.0f

typedef float v2f __attribute__((ext_vector_type(2)));

__device__ __forceinline__ float f4c(const float4 v, int c) {
    return c == 0 ? v.x : (c == 1 ? v.y : (c == 2 ? v.z : v.w));
}

// DPP helpers: full row/bank mask, bound_ctrl=1 -> old-value-independent
__device__ __forceinline__ float qp_xor1(float a) {   // quad_perm [1,0,3,2] = 0xB1
    return __int_as_float(__builtin_amdgcn_mov_dpp(__float_as_int(a), 0xB1, 0xF, 0xF, true));
}
__device__ __forceinline__ float qp_xor2(float a) {   // quad_perm [2,3,0,1] = 0x4E
    return __int_as_float(__builtin_amdgcn_mov_dpp(__float_as_int(a), 0x4E, 0xF, 0xF, true));
}
__device__ __forceinline__ float dpp_half_mirror(float a) {   // lane i <-> 7-i within 8
    return __int_as_float(__builtin_amdgcn_mov_dpp(__float_as_int(a), 0x141, 0xF, 0xF, true));
}
__device__ __forceinline__ float dpp_row_mirror(float a) {    // lane i <-> 15-i within 16
    return __int_as_float(__builtin_amdgcn_mov_dpp(__float_as_int(a), 0x140, 0xF, 0xF, true));
}

__global__ __launch_bounds__(256, 2) void dlgn_v22_kernel(
    const float* __restrict__ x,
    const float* __restrict__ W1,
    const float* __restrict__ W2,
    const float* __restrict__ W3,
    const float* __restrict__ V,
    float* __restrict__ out)
{
    __shared__ float xlds[8 * 160];   //  5120 B: kc-chunk stride 20
    __shared__ float Gs[8][100];      //  3200 B
    __shared__ float Plds[2560];      // 10240 B: per-thread stride 10

    const int t  = threadIdx.x;
    const int b0 = blockIdx.x * 8;

    // ---- Stage x tile: 1 float4/thread, coalesced; kc-skewed layout ----
    {
        const int r    = t >> 5;
        const int col4 = t & 31;
        const float4 xv = ((const float4*)(x + (size_t)(b0 + r) * 128))[col4];
        const int skc = col4 >> 2, sc = col4 & 3;
        *(float4*)&xlds[r * 160 + skc * 20 + sc * 4] = xv;
    }

    // ---- W chunks -> 48 registers (global, L2-resident) ----
    const int fl = t >> 3;   // feature-lane 0..31
    const int kc = t & 7;    // k-chunk 0..7
    float4 w1c[4], w2c[4], w3c[4];
    {
        const float4* W1r = (const float4*)(W1 + fl * 128 + kc * 16);
        const float4* W2r = (const float4*)(W2 + fl * 128 + kc * 16);
        const float4* W3r = (const float4*)(W3 + fl * 128 + kc * 16);
#pragma unroll
        for (int c = 0; c < 4; ++c) {
            w1c[c] = W1r[c]; w2c[c] = W2r[c]; w3c[c] = W3r[c];
        }
    }
    __syncthreads();   // xlds ready

    // ---- Phase 1: 8 rows x 3 matrices, packed k-eighth partial dots ----
    v2f acc2[3][8];
#pragma unroll
    for (int m = 0; m < 3; ++m)
#pragma unroll
        for (int r = 0; r < 8; ++r) acc2[m][r] = (v2f){0.f, 0.f};

#pragma unroll
    for (int r = 0; r < 8; ++r) {
        float4 xc[4];
#pragma unroll
        for (int c = 0; c < 4; ++c)
            xc[c] = *(const float4*)&xlds[r * 160 + kc * 20 + c * 4];
#pragma unroll
        for (int c = 0; c < 4; ++c) {
            const v2f xlo = (v2f){xc[c].x, xc[c].y};
            const v2f xhi = (v2f){xc[c].z, xc[c].w};
            acc2[0][r] = __builtin_elementwise_fma((v2f){w1c[c].x, w1c[c].y}, xlo, acc2[0][r]);
            acc2[0][r] = __builtin_elementwise_fma((v2f){w1c[c].z, w1c[c].w}, xhi, acc2[0][r]);
            acc2[1][r] = __builtin_elementwise_fma((v2f){w2c[c].x, w2c[c].y}, xlo, acc2[1][r]);
            acc2[1][r] = __builtin_elementwise_fma((v2f){w2c[c].z, w2c[c].w}, xhi, acc2[1][r]);
            acc2[2][r] = __builtin_elementwise_fma((v2f){w3c[c].x, w3c[c].y}, xlo, acc2[2][r]);
            acc2[2][r] = __builtin_elementwise_fma((v2f){w3c[c].z, w3c[c].w}, xhi, acc2[2][r]);
        }
    }

    // ---- Issue V loads now (W regs dead): slice (8i x 4j x 4k) per thread ----
    const int jg = (t >> 3) & 7;    // j group: 4*jg .. 4*jg+3
    const int ig = t >> 6;          // i group (wave-uniform): 8*ig .. 8*ig+7
    const float4* V4 = (const float4*)V;   // f4 idx = i*256 + j*8 + kc
    float4 v[32];                   // v[ii*4 + jj]
#pragma unroll
    for (int ii = 0; ii < 8; ++ii)
#pragma unroll
        for (int jj = 0; jj < 4; ++jj)
            v[ii * 4 + jj] = V4[(ig * 8 + ii) * 256 + (jg * 4 + jj) * 8 + kc];

    // ---- Combine k-eighths: PURE VALU (DPP xor1, xor2, half-mirror); sigmoid -> Gs ----
#pragma unroll
    for (int m = 0; m < 3; ++m) {
        float sel = 0.f;
#pragma unroll
        for (int r = 0; r < 8; ++r) {
            float a = acc2[m][r].x + acc2[m][r].y;
            a += qp_xor1(a);
            a += qp_xor2(a);          // each quad holds its quad-sum
            a += dpp_half_mirror(a);  // + opposite quad -> full 8-sum
            if (kc == r) sel = a;     // static select chain
        }
        Gs[kc][32 * m + fl] = 1.0f / (1.0f + __expf(-BETA * sel));
    }
    __syncthreads();

    // ---- Phase 2: per b only 4 LDS reads (g1 x2 uniform, g2, g3) + 84 VALU ----
    float p8[8];
#pragma unroll
    for (int b = 0; b < 8; ++b) {
        const float4 ga  = *(const float4*)&Gs[b][8 * ig];        // g1[8ig..+3], uniform
        const float4 gb  = *(const float4*)&Gs[b][8 * ig + 4];    // g1[8ig+4..+7], uniform
        const float4 g2r = *(const float4*)&Gs[b][32 + 4 * jg];   // 8-addr multicast
        const float4 g3r = *(const float4*)&Gs[b][64 + 4 * kc];   // 8-addr multicast

        float p = 0.f;
#pragma unroll
        for (int jj = 0; jj < 4; ++jj) {
            v2f wa = (v2f){0.f, 0.f};
            v2f wb = (v2f){0.f, 0.f};
#pragma unroll
            for (int ii = 0; ii < 8; ++ii) {
                const float g1i = (ii < 4) ? f4c(ga, ii & 3) : f4c(gb, ii & 3);
                const v2f g1v = (v2f){g1i, g1i};
                const float4 vv = v[ii * 4 + jj];
                wa = __builtin_elementwise_fma(g1v, (v2f){vv.x, vv.y}, wa);
                wb = __builtin_elementwise_fma(g1v, (v2f){vv.z, vv.w}, wb);
            }
            float d = wa.x * g3r.x;
            d = fmaf(wa.y, g3r.y, d);
            d = fmaf(wb.x, g3r.z, d);
            d = fmaf(wb.y, g3r.w, d);
            p = fmaf(f4c(g2r, jj), d, p);
        }
        p8[b] = p;
    }

    // ---- Deferred reduction: 2 packed b128 writes, barrier, DPP-heavy final pass ----
    *(float4*)&Plds[t * 10]     = make_float4(p8[0], p8[1], p8[2], p8[3]);
    *(float4*)&Plds[t * 10 + 4] = make_float4(p8[4], p8[5], p8[6], p8[7]);
    __syncthreads();

    {
        const int fb2 = t >> 5;   // b index 0..7
        const int pt  = t & 31;   // partial index
        float s = 0.f;
#pragma unroll
        for (int s8 = 0; s8 < 8; ++s8)
            s += Plds[(pt + s8 * 32) * 10 + fb2];
        s += qp_xor1(s);
        s += qp_xor2(s);
        s += dpp_half_mirror(s);   // 8-sum
        s += dpp_row_mirror(s);    // 16-sum
        s += __shfl_xor(s, 16);    // 32-sum (crosses DPP row boundary)
        if (pt == 0) out[b0 + fb2] = s;
    }
}

extern "C" void kernel_launch(void* const* d_in, const int* in_sizes, int n_in,
                              void* d_out, int out_size, void* d_ws, size_t ws_size,
                              hipStream_t stream) {
    const float* x  = (const float*)d_in[0];
    const float* W1 = (const float*)d_in[1];
    const float* W2 = (const float*)d_in[2];
    const float* W3 = (const float*)d_in[3];
    const float* V  = (const float*)d_in[4];
    float* out = (float*)d_out;

    dlgn_v22_kernel<<<dim3(512), dim3(256), 0, stream>>>(x, W1, W2, W3, V, out);
}

// Round 25
// 12.430 us; speedup vs baseline: 1.3100x; 1.3100x over previous
//
#include <hip/hip_runtime.h>

// DLGN_VT v23 (= v18, best known: 12.43 us) — terminal revert after v22's
// coalescing regression (8-segment wave-loads octupled TA requests).
//   512 blocks x 256 thr, 8 rows/block, launch_bounds(256,2). LDS 18.6 KB.
//   Phase 1: thread (fl=t>>3, kc=t&7) holds W1/2/3 chunks in 48 regs;
//     x kc-skewed in LDS; 8 rows x 24 pk-FMA; combine k-eighths PURE VALU
//     (DPP quad_perm xor1/xor2 + ROW_HALF_MIRROR); sigmoid -> Gs[8][100].
//   V loads issued after phase-1 FMA (contiguous 1KB/wave-instr, disjoint).
//   Phase 2: per b: g1 row via 8 uniform-broadcast ds_read_b128; g2 b32 +
//     g3 b128; 64 pk-FMA i-first; p8[b] in regs.
//   Reduce: p8 -> Plds (stride 10), barrier, 8 reads + DPP + shfl xor16 -> out.
// No atomics, no memset, no global scratch.

#define BETA 30.0f

typedef float v2f __attribute__((ext_vector_type(2)));

__device__ __forceinline__ float f4c(const float4 v, int c) {
    return c == 0 ? v.x : (c == 1 ? v.y : (c == 2 ? v.z : v.w));
}

// DPP helpers: full row/bank mask, bound_ctrl=1 -> old-value-independent
__device__ __forceinline__ float qp_xor1(float a) {   // quad_perm [1,0,3,2] = 0xB1
    return __int_as_float(__builtin_amdgcn_mov_dpp(__float_as_int(a), 0xB1, 0xF, 0xF, true));
}
__device__ __forceinline__ float qp_xor2(float a) {   // quad_perm [2,3,0,1] = 0x4E
    return __int_as_float(__builtin_amdgcn_mov_dpp(__float_as_int(a), 0x4E, 0xF, 0xF, true));
}
__device__ __forceinline__ float dpp_half_mirror(float a) {   // lane i <-> 7-i within 8
    return __int_as_float(__builtin_amdgcn_mov_dpp(__float_as_int(a), 0x141, 0xF, 0xF, true));
}
__device__ __forceinline__ float dpp_row_mirror(float a) {    // lane i <-> 15-i within 16
    return __int_as_float(__builtin_amdgcn_mov_dpp(__float_as_int(a), 0x140, 0xF, 0xF, true));
}

__global__ __launch_bounds__(256, 2) void dlgn_v23_kernel(
    const float* __restrict__ x,
    const float* __restrict__ W1,
    const float* __restrict__ W2,
    const float* __restrict__ W3,
    const float* __restrict__ V,
    float* __restrict__ out)
{
    __shared__ float xlds[8 * 160];   //  5120 B: kc-chunk stride 20
    __shared__ float Gs[8][100];      //  3200 B
    __shared__ float Plds[2560];      // 10240 B: per-thread stride 10

    const int t  = threadIdx.x;
    const int b0 = blockIdx.x * 8;

    // ---- Stage x tile: 1 float4/thread, coalesced; kc-skewed layout ----
    {
        const int r    = t >> 5;
        const int col4 = t & 31;
        const float4 xv = ((const float4*)(x + (size_t)(b0 + r) * 128))[col4];
        const int skc = col4 >> 2, sc = col4 & 3;
        *(float4*)&xlds[r * 160 + skc * 20 + sc * 4] = xv;
    }

    // ---- W chunks -> 48 registers (global, L2-resident) ----
    const int fl = t >> 3;   // feature-lane 0..31
    const int kc = t & 7;    // k-chunk 0..7
    float4 w1c[4], w2c[4], w3c[4];
    {
        const float4* W1r = (const float4*)(W1 + fl * 128 + kc * 16);
        const float4* W2r = (const float4*)(W2 + fl * 128 + kc * 16);
        const float4* W3r = (const float4*)(W3 + fl * 128 + kc * 16);
#pragma unroll
        for (int c = 0; c < 4; ++c) {
            w1c[c] = W1r[c]; w2c[c] = W2r[c]; w3c[c] = W3r[c];
        }
    }
    __syncthreads();   // xlds ready

    // ---- Phase 1: 8 rows x 3 matrices, packed k-eighth partial dots ----
    v2f acc2[3][8];
#pragma unroll
    for (int m = 0; m < 3; ++m)
#pragma unroll
        for (int r = 0; r < 8; ++r) acc2[m][r] = (v2f){0.f, 0.f};

#pragma unroll
    for (int r = 0; r < 8; ++r) {
        float4 xc[4];
#pragma unroll
        for (int c = 0; c < 4; ++c)
            xc[c] = *(const float4*)&xlds[r * 160 + kc * 20 + c * 4];
#pragma unroll
        for (int c = 0; c < 4; ++c) {
            const v2f xlo = (v2f){xc[c].x, xc[c].y};
            const v2f xhi = (v2f){xc[c].z, xc[c].w};
            acc2[0][r] = __builtin_elementwise_fma((v2f){w1c[c].x, w1c[c].y}, xlo, acc2[0][r]);
            acc2[0][r] = __builtin_elementwise_fma((v2f){w1c[c].z, w1c[c].w}, xhi, acc2[0][r]);
            acc2[1][r] = __builtin_elementwise_fma((v2f){w2c[c].x, w2c[c].y}, xlo, acc2[1][r]);
            acc2[1][r] = __builtin_elementwise_fma((v2f){w2c[c].z, w2c[c].w}, xhi, acc2[1][r]);
            acc2[2][r] = __builtin_elementwise_fma((v2f){w3c[c].x, w3c[c].y}, xlo, acc2[2][r]);
            acc2[2][r] = __builtin_elementwise_fma((v2f){w3c[c].z, w3c[c].w}, xhi, acc2[2][r]);
        }
    }

    // ---- Issue V loads now (W regs dead); complete under combine + barrier ----
    const float4* V4 = (const float4*)V;   // f4 idx = i*256 + t
    float4 v[32];
#pragma unroll
    for (int i = 0; i < 32; ++i) v[i] = V4[i * 256 + t];

    // ---- Combine k-eighths: PURE VALU (DPP xor1, xor2, half-mirror); sigmoid -> Gs ----
#pragma unroll
    for (int m = 0; m < 3; ++m) {
        float sel = 0.f;
#pragma unroll
        for (int r = 0; r < 8; ++r) {
            float a = acc2[m][r].x + acc2[m][r].y;
            a += qp_xor1(a);
            a += qp_xor2(a);          // each quad holds its quad-sum
            a += dpp_half_mirror(a);  // + opposite quad -> full 8-sum
            if (kc == r) sel = a;     // static select chain
        }
        Gs[kc][32 * m + fl] = 1.0f / (1.0f + __expf(-BETA * sel));
    }
    __syncthreads();

    // ---- Phase 2: thread = (j = t>>3, c2 = t&7); g1 via LDS broadcast into VGPRs ----
    const int j  = t >> 3;   // [0,32)
    const int c2 = t & 7;    // [0,8)

    float p8[8];
#pragma unroll
    for (int b = 0; b < 8; ++b) {
        const float4* Gr = (const float4*)&Gs[b][0];
        float4 g1r[8];
#pragma unroll
        for (int c = 0; c < 8; ++c) g1r[c] = Gr[c];    // uniform broadcast, conflict-free
        const float  g2s = Gs[b][32 + j];
        const float4 g3r = *(const float4*)&Gs[b][64 + c2 * 4];

        v2f u2a = (v2f){0.f, 0.f};   // {x,y} accumulator
        v2f u2b = (v2f){0.f, 0.f};   // {z,w} accumulator
#pragma unroll
        for (int i = 0; i < 32; ++i) {
            const float g1i = f4c(g1r[i >> 2], i & 3);   // static reg pick
            const v2f g1v = (v2f){g1i, g1i};
            u2a = __builtin_elementwise_fma(g1v, (v2f){v[i].x, v[i].y}, u2a);
            u2b = __builtin_elementwise_fma(g1v, (v2f){v[i].z, v[i].w}, u2b);
        }
        float s = u2a.x * g3r.x;
        s = fmaf(u2a.y, g3r.y, s);
        s = fmaf(u2b.x, g3r.z, s);
        s = fmaf(u2b.y, g3r.w, s);
        p8[b] = s * g2s;
    }

    // ---- Deferred reduction: 2 packed b128 writes, barrier, DPP-heavy final pass ----
    *(float4*)&Plds[t * 10]     = make_float4(p8[0], p8[1], p8[2], p8[3]);
    *(float4*)&Plds[t * 10 + 4] = make_float4(p8[4], p8[5], p8[6], p8[7]);
    __syncthreads();

    {
        const int fb2 = t >> 5;   // b index 0..7
        const int pt  = t & 31;   // partial index
        float s = 0.f;
#pragma unroll
        for (int s8 = 0; s8 < 8; ++s8)
            s += Plds[(pt + s8 * 32) * 10 + fb2];
        s += qp_xor1(s);
        s += qp_xor2(s);
        s += dpp_half_mirror(s);   // 8-sum
        s += dpp_row_mirror(s);    // 16-sum
        s += __shfl_xor(s, 16);    // 32-sum (crosses DPP row boundary)
        if (pt == 0) out[b0 + fb2] = s;
    }
}

extern "C" void kernel_launch(void* const* d_in, const int* in_sizes, int n_in,
                              void* d_out, int out_size, void* d_ws, size_t ws_size,
                              hipStream_t stream) {
    const float* x  = (const float*)d_in[0];
    const float* W1 = (const float*)d_in[1];
    const float* W2 = (const float*)d_in[2];
    const float* W3 = (const float*)d_in[3];
    const float* V  = (const float*)d_in[4];
    float* out = (float*)d_out;

    dlgn_v23_kernel<<<dim3(512), dim3(256), 0, stream>>>(x, W1, W2, W3, V, out);
}